// Round 4
// baseline (131.289 us; speedup 1.0000x reference)
//
#include <hip/hip_runtime.h>
#include <math.h>

// HOG-3D: central differences -> (theta,phi) soft-binned histogram scatter.
// Output (1,8,8,78,78,78) fp32 = 121.5 MB. Write-roofline ~19 us @ 6.5 TB/s.
//
// R3 changes vs R2 (which PASSED at 131 us, absmax 0.0156):
//  - float4 column stores: each thread owns 4 consecutive voxels and writes
//    one float4 per (t,p) plane -> 16 B/lane (the measured-peak store width)
//    instead of 4 B/lane dword streams.
//  - f32 fast path for atan2/acos with a 1e-4 bin-boundary guard (libm err
//    <= ~4e-6 in t_raw/p_raw units); only near-boundary voxels (~4e-4 of all)
//    redo the R2-exact correctly-rounded chain (f64 libm -> f32). Bin indices
//    provably identical; weight perturbation <= ~1e-4 << 0.249 threshold.
//  - 64-thread blocks (1854 blocks) to avoid 2-vs-1 blocks/CU imbalance.
// Numerics chain otherwise identical to the passing R2 kernel.

#define DVOL 64
#define S 78               // 64 + 2*8 - 2
#define S3 (S * S * S)     // 474552
#define NQ (S3 / 4)        // 118638 float4-quads per plane (exact)

__device__ __forceinline__ float ldx(const float* __restrict__ x, int z, int y, int xx) {
    if ((unsigned)z < (unsigned)DVOL && (unsigned)y < (unsigned)DVOL && (unsigned)xx < (unsigned)DVOL)
        return x[(z * DVOL + y) * DVOL + xx];
    return 0.0f;
}

__device__ __forceinline__ void analyze(const float* __restrict__ x, int idx,
                                        int& bo0, int& bo1, int& bo2,
                                        float& wo0, float& wo1, float& wo2) {
#pragma clang fp contract(off)
    int ox = idx % S;
    int r  = idx / S;
    int oy = r % S;
    int oz = r / S;
    int ix = ox - 7, iy = oy - 7, iz = oz - 7;

    // f32 central differences (IEEE subtract == numpy bitwise)
    float gz = ldx(x, iz + 1, iy, ix) - ldx(x, iz - 1, iy, ix);
    float gy = ldx(x, iz, iy + 1, ix) - ldx(x, iz, iy - 1, ix);
    float gx = ldx(x, iz, iy, ix + 1) - ldx(x, iz, iy, ix - 1);

    // ((c0^2 + c1^2) + c2^2) in f32, no FMA contraction
    float mag2 = (gz * gz + gy * gy) + gx * gx;
    float mag  = sqrtf(mag2);

    bo0 = bo1 = bo2 = -1;
    wo0 = wo1 = wo2 = 0.0f;
    if (mag == 0.0f) return;

    const float EPS32 = 2.220446049250313e-16f;   // 2^-52, exact in f32
    const float PI32  = 3.14159274101257324f;     // (float)math.pi
    float denom = mag + EPS32;                    // f32 add (== numpy)
    float ratio = gz / denom;                     // IEEE f32 divide (== numpy)

    // fast path: device f32 libm (<=2 ulp). Bin decisions only differ from
    // the correctly-rounded reference within ~4e-6 of an integer boundary.
    float theta = atan2f(gy, gx);
    float phi   = acosf(ratio);
    float t_raw = theta / PI32 * 8.0f;
    float p_raw = phi   / PI32 * 8.0f;

    float td = fabsf(t_raw - rintf(t_raw));
    float pd = fabsf(p_raw - rintf(p_raw));
    if (td < 1e-4f || pd < 1e-4f) {
        // near-boundary: exact R2 chain -- correctly-rounded f32 via f64 libm
        theta = (float)atan2((double)gy, (double)gx);
        phi   = (float)acos((double)ratio);
        t_raw = theta / PI32 * 8.0f;
        p_raw = phi   / PI32 * 8.0f;
    }

    float t_frac = t_raw - truncf(t_raw);         // torch.frac (signed), exact
    float p_frac = p_raw - truncf(p_raw);

    // numpy floored-mod, pow2 divisor -> two's-complement AND
    int i0 = ((int)floorf(t_raw)) & 7;
    int i1 = ((int)ceilf (t_raw)) & 7;
    int i2 = ((int)floorf(p_raw)) & 7;
    int i3 = ((int)ceilf (p_raw)) & 7;

    float f0 = fabsf(t_frac), f1 = fabsf(1.0f - t_frac);
    float f2 = fabsf(p_frac), f3 = fabsf(1.0f - p_frac);
    float w0 = (f0 * f2) * mag;   // -> (i0, i2)
    float w1 = (f0 * f3) * mag;   // -> (i0, i3)
    float w2 = (f1 * f2) * mag;   // -> (i1, i2)

    int b0 = i0 * 8 + i2, b1 = i0 * 8 + i3, b2 = i1 * 8 + i2;
    // merge colliding deposits in the reference add order ((w0+w1)+w2)
    if (b1 == b0) { w0 = w0 + w1; b1 = -1; }
    if (b2 == b0) { w0 = w0 + w2; b2 = -1; }
    // (b2==b1 with b1!=b0 impossible: needs i1==i0 && i3==i2 -> b1==b0)

    bo0 = b0; bo1 = b1; bo2 = b2;
    wo0 = w0; wo1 = w1; wo2 = w2;
}

__global__ void __launch_bounds__(64) hog4(const float* __restrict__ x,
                                           float4* __restrict__ out4) {
    int t = blockIdx.x * 64 + threadIdx.x;
    if (t >= NQ) return;
    int base = t * 4;

    int   b[4][3];
    float w[4][3];
    #pragma unroll
    for (int v = 0; v < 4; ++v)
        analyze(x, base + v, b[v][0], b[v][1], b[v][2], w[v][0], w[v][1], w[v][2]);

    // write the full 64-plane column as float4 (16 B/lane, coalesced 1 KB/wave)
    #pragma unroll
    for (int p = 0; p < 64; ++p) {
        float4 val = make_float4(0.0f, 0.0f, 0.0f, 0.0f);
        #pragma unroll
        for (int d = 0; d < 3; ++d) {
            if (b[0][d] == p) val.x = w[0][d];
            if (b[1][d] == p) val.y = w[1][d];
            if (b[2][d] == p) val.z = w[2][d];
            if (b[3][d] == p) val.w = w[3][d];
        }
        out4[(size_t)p * NQ + t] = val;
    }
}

extern "C" void kernel_launch(void* const* d_in, const int* in_sizes, int n_in,
                              void* d_out, int out_size, void* d_ws, size_t ws_size,
                              hipStream_t stream) {
    const float* x = (const float*)d_in[0];   // (64,64,64) fp32
    // d_in[1] (sobel weight) is a fixed constant per the reference -- folded in.
    float4* out4 = (float4*)d_out;

    const int threads = 64;                   // 1-wave blocks: balanced ~7 blocks/CU
    const int blocks = (NQ + threads - 1) / threads;   // 1854
    hog4<<<blocks, threads, 0, stream>>>(x, out4);
}